// Round 13
// baseline (436.268 us; speedup 1.0000x reference)
//
#include <hip/hip_runtime.h>

typedef __fp16 f16x2 __attribute__((ext_vector_type(2)));

#define Dm 128
#define Bn 16
#define VOX (Dm * Dm * Dm)
#define NT 256
#define RSTR 38          // LDS row stride in words (EVEN -> 8B-aligned b64 reads)
#define SLAB 1216        // 32 rows x 38 words (rows 30,31 = staging pad)
#define NPS 9            // staged word-pairs per thread (9*64=576 >= 540)

__device__ __forceinline__ int iclamp(int v, int lo, int hi) {
  return v < lo ? lo : (v > hi ? hi : v);
}
__device__ __forceinline__ f16x2 pkrtz(float lo, float hi) {
  return __builtin_amdgcn_cvt_pkrtz(lo, hi);
}
__device__ __forceinline__ float pkbits(float lo, float hi) {
  return __builtin_bit_cast(float, __builtin_amdgcn_cvt_pkrtz(lo, hi));
}
__device__ __forceinline__ f16x2 asf16x2(float w) {
  return __builtin_bit_cast(f16x2, w);
}
// half-broadcasts: fold into VOP3P op_sel (no extra instr)
__device__ __forceinline__ f16x2 duplo(f16x2 v) {
  return __builtin_shufflevector(v, v, 0, 0);
}
__device__ __forceinline__ f16x2 duphi(f16x2 v) {
  return __builtin_shufflevector(v, v, 1, 1);
}
// keep a loaded value live HERE: blocks the compiler from sinking the load
// to its use point (which silently deletes the software pipeline — R11).
__device__ __forceinline__ void keep(float& a) {
  asm volatile("" : "+v"(a));
}

// W transposed (wpkT[t*27+o] = W[o][t]) + bias, duplicated-half f16x2.
extern "C" __global__ void packW(const float* __restrict__ Wf,
                                 const float* __restrict__ bfp,
                                 float* __restrict__ wpk) {
  int i = threadIdx.x;
  if (i < 729) {
    int o = i / 27, t = i - o * 27;
    float v = Wf[i];
    wpk[t * 27 + o] = pkbits(v, v);
  } else if (i < 756) {
    float b = bfp[i - 729];
    wpk[i] = pkbits(b, b);
  }
}

// Batch-pair packed apply: LDS word v = (x_b[v], x_{b+1}[v]) f16x2.
// One stencil read serves TWO batches; no cross-voxel perms; K broadcast
// per voxel via op_sel. Wave-private slab (own z+-1 halo), zero barriers.
extern "C" __global__ void __launch_bounds__(NT, 4)
fused3d(const float* __restrict__ img, const float* __restrict__ x,
        const float* __restrict__ wpk, float* __restrict__ out)
{
  __shared__ float sX[4][SLAB];    // 19456 B

  const int tid  = threadIdx.x;
  const int lane = tid & 63;
  const int wv   = tid >> 6;       // wave id == z offset within block tile
  const int tx   = lane & 7;       // w-quad 0..7 (voxels 4tx..4tx+3)
  const int ty   = lane >> 3;      // h 0..7

  // T1 XCD swizzle: contiguous slab of 256 tiles per XCD
  const int bid = blockIdx.x;                 // 0..2047
  const int s  = (bid & 7) * 256 + (bid >> 3);
  const int bx = s & 3, by = (s >> 2) & 15, bz = s >> 6;
  const int w0 = bx * 32, h0 = by * 8, d0 = bz * 4;

  const int od = d0 + wv, oh = h0 + ty, ow = w0 + 4 * tx;

  // ---- staging map: pair j = 64k+lane -> row r=j/18 (zz=r/10, yy=r%10),
  // pair-col pc=j%18. LDS words (r*RSTR+2pc, +1) hold global w (w0-2+2pc, +1).
  // So LDS word m within a row = global w - w0 + 2. Rows 30,31 = pad.
  int goff[NPS], lofs[NPS];
#pragma unroll
  for (int k = 0; k < NPS; ++k) {
    int j  = 64 * k + lane;
    int r  = j / 18;
    int pc = j - r * 18;
    int zz = r / 10;
    int yy = r - zz * 10;
    int gd = iclamp(d0 + wv + zz - 1, 0, Dm - 1);
    int gh = iclamp(h0 + yy - 1, 0, Dm - 1);
    int gw = iclamp(w0 - 2 + 2 * pc, 0, Dm - 2);   // even: keeps 8B alignment
    goff[k] = (gd * Dm + gh) * Dm + gw;
    lofs[k] = r * RSTR + 2 * pc;                   // CONSISTENT with read side
  }

  float* sl = sX[wv];

  // ---- issue pair-0 loads FIRST (K-gen ~1600cy covers HBM latency),
  // keep-alives pin them hoisted (anti-sinking).
  float2 nb[NPS], nc[NPS];
#pragma unroll
  for (int k = 0; k < NPS; ++k) {
    nb[k] = *(const float2*)(x + goff[k]);
    nc[k] = *(const float2*)(x + VOX + goff[k]);
    keep(nb[k].x); keep(nb[k].y); keep(nc[k].x); keep(nc[k].y);
  }

  // ---- K-gen from GLOBAL img (L3-resident, once per block), packed fp16.
  // KA = (K[w], K[w+1]), KB = (K[w+2], K[w+3]); W rows contiguous via wpkT.
  f16x2 KA[27], KB[27];
#pragma unroll
  for (int o = 0; o < 27; ++o) { KA[o] = asf16x2(wpk[729 + o]); KB[o] = KA[o]; }
#pragma unroll
  for (int rr = 0; rr < 9; ++rr) {
    const int zz = rr / 3, dy = rr % 3;
    const int gd0 = od + zz - 1, gh0 = oh + dy - 1;
    const bool rk = ((unsigned)gd0 < Dm) & ((unsigned)gh0 < Dm);
    const float* rp = img + ((size_t)iclamp(gd0, 0, Dm - 1) * Dm
                             + iclamp(gh0, 0, Dm - 1)) * Dm;
    float v[6];
#pragma unroll
    for (int c = 0; c < 6; ++c) {
      int gw = ow + c - 1;
      v[c] = (rk & ((unsigned)gw < Dm)) ? rp[iclamp(gw, 0, Dm - 1)] : 0.f;
    }
    f16x2 mA0 = pkrtz(v[0], v[1]), mA1 = pkrtz(v[1], v[2]);
    f16x2 mA2 = pkrtz(v[2], v[3]);                  // == mB0
    f16x2 mB1 = pkrtz(v[3], v[4]), mB2 = pkrtz(v[4], v[5]);
    const float* wA = wpk + (rr * 3 + 0) * 27;
    const float* wB = wpk + (rr * 3 + 1) * 27;
    const float* wC = wpk + (rr * 3 + 2) * 27;
#pragma unroll
    for (int o = 0; o < 27; ++o) {
      f16x2 wa = asf16x2(wA[o]), wb = asf16x2(wB[o]), wc = asf16x2(wC[o]);
      KA[o] = __builtin_elementwise_fma(wa, mA0, KA[o]);
      KA[o] = __builtin_elementwise_fma(wb, mA1, KA[o]);
      KA[o] = __builtin_elementwise_fma(wc, mA2, KA[o]);
      KB[o] = __builtin_elementwise_fma(wa, mA2, KB[o]);
      KB[o] = __builtin_elementwise_fma(wb, mB1, KB[o]);
      KB[o] = __builtin_elementwise_fma(wc, mB2, KB[o]);
    }
  }

  // ---- boundary tap masks (x zero-pad semantics; kills bias too)
#pragma unroll
  for (int o = 0; o < 27; ++o) {
    const int di = o / 9, dj = (o / 3) % 3, dk = o % 3;
    const bool mm = ((unsigned)(od + di - 1) < Dm) & ((unsigned)(oh + dj - 1) < Dm);
    const float a0 = (mm & ((unsigned)(ow + dk - 1) < Dm)) ? 1.f : 0.f;
    const float a1 = (mm & ((unsigned)(ow + dk)     < Dm)) ? 1.f : 0.f;
    const float b0 = (mm & ((unsigned)(ow + dk + 1) < Dm)) ? 1.f : 0.f;
    const float b1 = (mm & ((unsigned)(ow + dk + 2) < Dm)) ? 1.f : 0.f;
    KA[o] *= pkrtz(a0, a1);
    KB[o] *= pkrtz(b0, b1);
  }

  const size_t obase = (((size_t)od) * Dm + oh) * Dm + ow;  // 16B aligned
  const int rbase = 4 * tx;   // word m = 4tx..4tx+7 covers w = ow-1..ow+4 (+pad)

  // ---- batch-pair loop (8 iters): stage pp -> issue loads pp+1 -> apply pp.
  // Wave-private slab: in-wave LDS ordering handles WAR, no barriers.
#pragma unroll 1
  for (int pp = 0; pp < Bn / 2; ++pp) {
    // stage: (pk(xb,xc) of w, pk of w+1) -> ds_write_b64 at lofs
#pragma unroll
    for (int k = 0; k < NPS; ++k) {
      float2 wp;
      wp.x = pkbits(nb[k].x, nc[k].x);
      wp.y = pkbits(nb[k].y, nc[k].y);
      *(float2*)&sl[lofs[k]] = wp;
    }

    if (pp + 1 < Bn / 2) {          // issue next pair's loads, pin hoisted
      const float* xb = x + (size_t)(2 * pp + 2) * VOX;
#pragma unroll
      for (int k = 0; k < NPS; ++k) {
        nb[k] = *(const float2*)(xb + goff[k]);
        nc[k] = *(const float2*)(xb + VOX + goff[k]);
        keep(nb[k].x); keep(nb[k].y); keep(nc[k].x); keep(nc[k].y);
      }
    }

    // apply: per rr read 8 aligned words (2x ds_read2_b64), 12 pk_fma
    f16x2 acc0 = {(__fp16)0.f, (__fp16)0.f};
    f16x2 acc1 = acc0, acc2 = acc0, acc3 = acc0;
#pragma unroll
    for (int rr = 0; rr < 9; ++rr) {
      const int row  = (rr / 3) * 10 + ty + (rr % 3);
      const int base = row * RSTR + rbase;
      float2 qa = *(const float2*)&sl[base];       // m = 4tx,   4tx+1
      float2 qb = *(const float2*)&sl[base + 2];   // m = 4tx+2, 4tx+3
      float2 qc = *(const float2*)&sl[base + 4];   // m = 4tx+4, 4tx+5
      float2 qd = *(const float2*)&sl[base + 6];   // m = 4tx+6, 4tx+7
      f16x2 U1 = asf16x2(qa.y);  // w-1  (m = 4tx+1 -> w = w0+4tx-1)
      f16x2 U2 = asf16x2(qb.x);  // w
      f16x2 U3 = asf16x2(qb.y);  // w+1
      f16x2 U4 = asf16x2(qc.x);  // w+2
      f16x2 U5 = asf16x2(qc.y);  // w+3
      f16x2 U6 = asf16x2(qd.x);  // w+4
      f16x2 Uv[6] = {U1, U2, U3, U4, U5, U6};
#pragma unroll
      for (int dk = 0; dk < 3; ++dk) {
        const int t = rr * 3 + dk;
        acc0 = __builtin_elementwise_fma(duplo(KA[t]), Uv[0 + dk], acc0);
        acc1 = __builtin_elementwise_fma(duphi(KA[t]), Uv[1 + dk], acc1);
        acc2 = __builtin_elementwise_fma(duplo(KB[t]), Uv[2 + dk], acc2);
        acc3 = __builtin_elementwise_fma(duphi(KB[t]), Uv[3 + dk], acc3);
      }
    }

    float4 s0, s1;
    s0.x = (float)acc0.x; s0.y = (float)acc1.x;
    s0.z = (float)acc2.x; s0.w = (float)acc3.x;
    s1.x = (float)acc0.y; s1.y = (float)acc1.y;
    s1.z = (float)acc2.y; s1.w = (float)acc3.y;
    *(float4*)&out[(size_t)(2 * pp)     * VOX + obase] = s0;
    *(float4*)&out[(size_t)(2 * pp + 1) * VOX + obase] = s1;
  }
}

extern "C" void kernel_launch(void* const* d_in, const int* in_sizes, int n_in,
                              void* d_out, int out_size, void* d_ws, size_t ws_size,
                              hipStream_t stream) {
  const float* img = (const float*)d_in[0];
  const float* x   = (const float*)d_in[1];
  const float* Wf  = (const float*)d_in[2];
  const float* bf  = (const float*)d_in[3];
  float* out = (float*)d_out;
  float* wpk = (float*)d_ws;   // 756 floats: wpkT + bias, packed f16x2
  hipLaunchKernelGGL(packW, dim3(1), dim3(768), 0, stream, Wf, bf, wpk);
  // 2048 blocks: 4(w) x 16(h) x 32(z) tiles of 32w x 8y x 4z
  hipLaunchKernelGGL(fused3d, dim3(2048), dim3(NT), 0, stream, img, x, wpk, out);
}